// Round 2
// baseline (198.935 us; speedup 1.0000x reference)
//
#include <hip/hip_runtime.h>

typedef unsigned short ushort_t;
typedef __attribute__((ext_vector_type(8))) short bf16x8;
typedef __attribute__((ext_vector_type(8))) unsigned short u16x8;
typedef __attribute__((ext_vector_type(4))) float f32x4;

#define B_ 64
#define N_ 1024
#define C_ 128

static __device__ __forceinline__ float bf2f(unsigned short u) {
  union { unsigned int i; float f; } v; v.i = ((unsigned int)u) << 16; return v.f;
}
static __device__ __forceinline__ unsigned short f2bf(float f) {  // RNE
  union { float f; unsigned int i; } v; v.f = f;
  unsigned int i = v.i;
  return (unsigned short)((i + 0x7FFFu + ((i >> 16) & 1u)) >> 16);
}
// truncation split: x = hi + lo + eps, |eps| <= 2^-17 |x|
static __device__ __forceinline__ void split1(float x, ushort_t& h, ushort_t& l) {
  union { float f; unsigned int i; } u; u.f = x;
  h = (ushort_t)(u.i >> 16);
  union { unsigned int i; float f; } t; t.i = u.i & 0xFFFF0000u;
  union { float f; unsigned int i; } w; w.f = x - t.f;
  l = (ushort_t)(w.i >> 16);
}
static __device__ __forceinline__ bf16x8 as_bf(u16x8 v) {
  union { u16x8 u; bf16x8 b; } x; x.u = v; return x.b;
}
static __device__ __forceinline__ void gload_lds16(const void* g, void* l) {
  __builtin_amdgcn_global_load_lds((const __attribute__((address_space(1))) void*)g,
                                   (__attribute__((address_space(3))) void*)l,
                                   16, 0, 0);
}

// ---------------------------------------------------------------------------
// Transpose + split: src fp32 [rows][cols] -> dh/dl bf16 [cols][rows]
// ---------------------------------------------------------------------------
__global__ __launch_bounds__(256) void tsplit(const float* __restrict__ src,
                                              ushort_t* __restrict__ dh,
                                              ushort_t* __restrict__ dl,
                                              int rows, int cols, long sb, long db) {
  __shared__ float tile[64][65];
  const int t = threadIdx.x;
  src += (long)blockIdx.z * sb;
  dh  += (long)blockIdx.z * db;
  dl  += (long)blockIdx.z * db;
  const int r0 = blockIdx.y * 64, c0 = blockIdx.x * 64;
#pragma unroll
  for (int p = 0; p < 4; ++p) {
    int row = p * 16 + (t >> 4), c4 = (t & 15) * 4;
    f32x4 v = *(const f32x4*)(src + (long)(r0 + row) * cols + c0 + c4);
#pragma unroll
    for (int j = 0; j < 4; ++j) tile[row][c4 + j] = v[j];
  }
  __syncthreads();
  const int oc = t >> 2;
#pragma unroll
  for (int p = 0; p < 2; ++p) {
    int ck = (t & 3) + p * 4;
    u16x8 vh, vl;
#pragma unroll
    for (int j = 0; j < 8; ++j) {
      ushort_t hj, lj;
      split1(tile[ck * 8 + j][oc], hj, lj);
      vh[j] = hj; vl[j] = lj;
    }
    long o = (long)(c0 + oc) * rows + r0 + ck * 8;
    *(u16x8*)(dh + o) = vh;
    *(u16x8*)(dl + o) = vl;
  }
}

// ---------------------------------------------------------------------------
// GC GEMM: v[b] = adj[b] @ ann[b] + gc_bias  (fp32 in, fp32 out)
// A (adj fp32) reg-staged + truncation-split into swizzled LDS hi/lo.
// B (annT pre-split bf16) via global_load_lds with pre-swizzled source addr.
// 3-term split MFMA: Ah*Bh + Al*Bh + Ah*Bl.
// ---------------------------------------------------------------------------
__global__ __launch_bounds__(256, 2) void gc_gemm(const float* __restrict__ adj,
                                                  const ushort_t* __restrict__ annTh,
                                                  const ushort_t* __restrict__ annTl,
                                                  const float* __restrict__ gcb,
                                                  float* __restrict__ vout) {
  __shared__ __align__(16) ushort_t ldsAh[128 * 64];
  __shared__ __align__(16) ushort_t ldsAl[128 * 64];
  __shared__ __align__(16) ushort_t ldsBh[128 * 64];
  __shared__ __align__(16) ushort_t ldsBl[128 * 64];
  const int tid = threadIdx.x;
  const int w = tid >> 6, lane = tid & 63;
  const int wr = w >> 1, wc = w & 1;
  const int b = blockIdx.x >> 3;
  const int m0 = (blockIdx.x & 7) * 128;

  const float*    adjb = adj   + ((long)b * N_ + m0) * N_;  // [128][1024] fp32
  const ushort_t* aThb = annTh + (long)b * C_ * N_;         // [128][1024] bf16
  const ushort_t* aTlb = annTl + (long)b * C_ * N_;

  const int srow8 = lane >> 3;
  const int klog  = ((lane & 7) * 16) ^ (srow8 << 4);  // pre-swizzled src byte off
  const int fr = lane & 15;
  const int kg = lane >> 4;

  f32x4 acc[4][4] = {};

  for (int k0 = 0; k0 < N_; k0 += 64) {
    // B staging: direct-to-LDS, source address carries the XOR swizzle
#pragma unroll
    for (int jj = 0; jj < 4; ++jj) {
      int j = w * 4 + jj;
      long so = (long)(j * 8 + srow8) * N_ + k0 + (klog >> 1);
      gload_lds16(aThb + so, (void*)&ldsBh[j * 512]);
      gload_lds16(aTlb + so, (void*)&ldsBl[j * 512]);
    }
    // A staging: fp32 load -> split -> swizzled ds_write
#pragma unroll
    for (int q = 0; q < 4; ++q) {
      int ch = q * 256 + tid;
      int row = ch >> 3, ce = ch & 7;
      const float* g = adjb + (long)row * N_ + k0 + ce * 8;
      f32x4 a0 = *(const f32x4*)g;
      f32x4 a1 = *(const f32x4*)(g + 4);
      u16x8 vh, vl;
#pragma unroll
      for (int j = 0; j < 4; ++j) {
        ushort_t hj, lj;
        split1(a0[j], hj, lj); vh[j] = hj; vl[j] = lj;
        split1(a1[j], hj, lj); vh[4 + j] = hj; vl[4 + j] = lj;
      }
      int kb = (ce * 16) ^ ((row & 7) << 4);
      *(u16x8*)((char*)ldsAh + row * 128 + kb) = vh;
      *(u16x8*)((char*)ldsAl + row * 128 + kb) = vl;
    }
    __syncthreads();
#pragma unroll
    for (int kk = 0; kk < 2; ++kk) {
      bf16x8 ah[4], al[4], bh[4], bl[4];
#pragma unroll
      for (int mi = 0; mi < 4; ++mi) {
        int row = wr * 64 + mi * 16 + fr;
        int kb = (kk * 64 + kg * 16) ^ ((row & 7) << 4);
        ah[mi] = *(const bf16x8*)((const char*)ldsAh + row * 128 + kb);
        al[mi] = *(const bf16x8*)((const char*)ldsAl + row * 128 + kb);
      }
#pragma unroll
      for (int ni = 0; ni < 4; ++ni) {
        int row = wc * 64 + ni * 16 + fr;
        int kb = (kk * 64 + kg * 16) ^ ((row & 7) << 4);
        bh[ni] = *(const bf16x8*)((const char*)ldsBh + row * 128 + kb);
        bl[ni] = *(const bf16x8*)((const char*)ldsBl + row * 128 + kb);
      }
#pragma unroll
      for (int mi = 0; mi < 4; ++mi)
#pragma unroll
        for (int ni = 0; ni < 4; ++ni) {
          acc[mi][ni] = __builtin_amdgcn_mfma_f32_16x16x32_bf16(ah[mi], bh[ni], acc[mi][ni], 0, 0, 0);
          acc[mi][ni] = __builtin_amdgcn_mfma_f32_16x16x32_bf16(al[mi], bh[ni], acc[mi][ni], 0, 0, 0);
          acc[mi][ni] = __builtin_amdgcn_mfma_f32_16x16x32_bf16(ah[mi], bl[ni], acc[mi][ni], 0, 0, 0);
        }
    }
    __syncthreads();
  }

  const long rowbase = (long)b * N_ + m0 + wr * 64;
#pragma unroll
  for (int ni = 0; ni < 4; ++ni) {
    int col = wc * 64 + ni * 16 + fr;
    float bias = gcb[col];
#pragma unroll
    for (int mi = 0; mi < 4; ++mi)
#pragma unroll
      for (int r = 0; r < 4; ++r)
        vout[(rowbase + mi * 16 + kg * 4 + r) * C_ + col] = acc[mi][ni][r] + bias;
  }
}

// ---------------------------------------------------------------------------
// GRU single step (Keras reset_after), fp32 in/out.
// x (=v) split hi/lo (3-term MFMA vs split weights); h (=ann) single bf16 RNE
// vs hi weights only (hz scale ~1 => error ~2e-3, well under budget).
// ---------------------------------------------------------------------------
#define GATE(G, AK0, AK1, AR0, AR1)                                                         \
  do {                                                                                      \
    const ushort_t* kh_ = kTh + (long)((G) * C_ + cb) * C_;                                 \
    const ushort_t* kl_ = kTl + (long)((G) * C_ + cb) * C_;                                 \
    const ushort_t* rh_ = rTh + (long)((G) * C_ + cb) * C_;                                 \
    bf16x8 KH[4], KL[4], RH[4];                                                             \
    _Pragma("unroll")                                                                       \
    for (int kk = 0; kk < 4; ++kk) {                                                        \
      int o_ = kk * 32 + kg * 8;                                                            \
      KH[kk] = *(const bf16x8*)(kh_ + o_);                                                  \
      KL[kk] = *(const bf16x8*)(kl_ + o_);                                                  \
      RH[kk] = *(const bf16x8*)(rh_ + o_);                                                  \
    }                                                                                       \
    _Pragma("unroll")                                                                       \
    for (int kk = 0; kk < 4; ++kk) {                                                        \
      AK0 = __builtin_amdgcn_mfma_f32_16x16x32_bf16(xh[0][kk], KH[kk], AK0, 0, 0, 0);       \
      AK1 = __builtin_amdgcn_mfma_f32_16x16x32_bf16(xh[1][kk], KH[kk], AK1, 0, 0, 0);       \
      AK0 = __builtin_amdgcn_mfma_f32_16x16x32_bf16(xl[0][kk], KH[kk], AK0, 0, 0, 0);       \
      AK1 = __builtin_amdgcn_mfma_f32_16x16x32_bf16(xl[1][kk], KH[kk], AK1, 0, 0, 0);       \
      AK0 = __builtin_amdgcn_mfma_f32_16x16x32_bf16(xh[0][kk], KL[kk], AK0, 0, 0, 0);       \
      AK1 = __builtin_amdgcn_mfma_f32_16x16x32_bf16(xh[1][kk], KL[kk], AK1, 0, 0, 0);       \
    }                                                                                       \
    _Pragma("unroll")                                                                       \
    for (int kk = 0; kk < 4; ++kk) {                                                        \
      AR0 = __builtin_amdgcn_mfma_f32_16x16x32_bf16(hh[0][kk], RH[kk], AR0, 0, 0, 0);       \
      AR1 = __builtin_amdgcn_mfma_f32_16x16x32_bf16(hh[1][kk], RH[kk], AR1, 0, 0, 0);       \
    }                                                                                       \
  } while (0)

__global__ __launch_bounds__(256, 2) void gru(const float* __restrict__ v,
                                              const float* __restrict__ ann,
                                              const ushort_t* __restrict__ kTh,
                                              const ushort_t* __restrict__ kTl,
                                              const ushort_t* __restrict__ rTh,
                                              const float* __restrict__ gb,
                                              float* __restrict__ out) {
  const int w = threadIdx.x >> 6, lane = threadIdx.x & 63;
  const long m0 = ((long)blockIdx.x * 4 + w) * 32;
  const int fr = lane & 15, kg = lane >> 4;

  bf16x8 xh[2][4], xl[2][4], hh[2][4];
#pragma unroll
  for (int s = 0; s < 2; ++s)
#pragma unroll
    for (int kk = 0; kk < 4; ++kk) {
      long off = (m0 + s * 16 + fr) * (long)C_ + kk * 32 + kg * 8;
      f32x4 x0 = *(const f32x4*)(v + off);
      f32x4 x1 = *(const f32x4*)(v + off + 4);
      u16x8 th, tl;
#pragma unroll
      for (int j = 0; j < 4; ++j) {
        ushort_t hj, lj;
        split1(x0[j], hj, lj); th[j] = hj; tl[j] = lj;
        split1(x1[j], hj, lj); th[4 + j] = hj; tl[4 + j] = lj;
      }
      xh[s][kk] = as_bf(th); xl[s][kk] = as_bf(tl);
      f32x4 h0 = *(const f32x4*)(ann + off);
      f32x4 h1 = *(const f32x4*)(ann + off + 4);
      u16x8 hv;
#pragma unroll
      for (int j = 0; j < 4; ++j) { hv[j] = f2bf(h0[j]); hv[4 + j] = f2bf(h1[j]); }
      hh[s][kk] = as_bf(hv);
    }

#pragma unroll 1
  for (int n = 0; n < 8; ++n) {
    const int cb = n * 16 + fr;
    f32x4 az0 = {}, az1 = {}, ar0 = {}, ar1 = {}, ax0 = {}, ax1 = {}, ah0 = {}, ah1 = {};
    GATE(0, az0, az1, az0, az1);
    GATE(1, ar0, ar1, ar0, ar1);
    GATE(2, ax0, ax1, ah0, ah1);

    const float bz  = gb[cb] + gb[384 + cb];
    const float brr = gb[128 + cb] + gb[384 + 128 + cb];
    const float bxh = gb[256 + cb];
    const float bhi = gb[384 + 256 + cb];
#pragma unroll
    for (int s = 0; s < 2; ++s) {
      const f32x4& az_ = s ? az1 : az0;
      const f32x4& ar_ = s ? ar1 : ar0;
      const f32x4& ax_ = s ? ax1 : ax0;
      const f32x4& ah_ = s ? ah1 : ah0;
#pragma unroll
      for (int r = 0; r < 4; ++r) {
        long row = m0 + s * 16 + kg * 4 + r;
        float hval = ann[row * C_ + cb];
        float zz = 1.f / (1.f + __expf(-(az_[r] + bz)));
        float rr = 1.f / (1.f + __expf(-(ar_[r] + brr)));
        float hpre = ax_[r] + bxh + rr * (ah_[r] + bhi);
        hpre = fminf(fmaxf(hpre, -15.f), 15.f);
        float e2 = __expf(2.f * hpre);
        float th = (e2 - 1.f) / (e2 + 1.f);
        out[row * C_ + cb] = zz * hval + (1.f - zz) * th;
      }
    }
  }
}

// ---------------------------------------------------------------------------
extern "C" void kernel_launch(void* const* d_in, const int* in_sizes, int n_in,
                              void* d_out, int out_size, void* d_ws, size_t ws_size,
                              hipStream_t stream) {
  const float* adj = (const float*)d_in[0];
  const float* ann = (const float*)d_in[1];
  const float* gcb = (const float*)d_in[2];
  const float* ker = (const float*)d_in[3];
  const float* rk  = (const float*)d_in[4];
  const float* gb  = (const float*)d_in[5];
  float* out = (float*)d_out;

  char* ws = (char*)d_ws;
  ushort_t* annTh = (ushort_t*)(ws);                      // [64][128][1024] bf16, 16 MB
  ushort_t* annTl = (ushort_t*)(ws + 16777216);           // 16 MB
  ushort_t* kTh   = (ushort_t*)(ws + 33554432);           // [384][128]
  ushort_t* kTl   = (ushort_t*)(ws + 33652736);
  ushort_t* rTh   = (ushort_t*)(ws + 33751040);
  ushort_t* rTl   = (ushort_t*)(ws + 33849344);
  float*    v     = (float*)(ws + 33947648);              // [65536][128] fp32, 33.5 MB

  // ann [b][1024][128] -> annT hi/lo [b][128][1024]
  hipLaunchKernelGGL(tsplit, dim3(2, 16, 64), dim3(256), 0, stream,
                     ann, annTh, annTl, 1024, 128, (long)1024 * 128, (long)128 * 1024);
  // kernel/recurrent [128][384] -> [384][128] hi/lo
  hipLaunchKernelGGL(tsplit, dim3(6, 2, 1), dim3(256), 0, stream,
                     ker, kTh, kTl, 128, 384, 0L, 0L);
  hipLaunchKernelGGL(tsplit, dim3(6, 2, 1), dim3(256), 0, stream,
                     rk, rTh, rTl, 128, 384, 0L, 0L);
  // graph convolution
  hipLaunchKernelGGL(gc_gemm, dim3(512), dim3(256), 0, stream, adj, annTh, annTl, gcb, v);
  // GRU step
  hipLaunchKernelGGL(gru, dim3(512), dim3(256), 0, stream, v, ann, kTh, kTl, rTh, gb, out);
}

// Round 3
// 164.987 us; speedup vs baseline: 1.2058x; 1.2058x over previous
//
#include <hip/hip_runtime.h>

typedef unsigned short ushort_t;
typedef __attribute__((ext_vector_type(8))) short bf16x8;
typedef __attribute__((ext_vector_type(8))) unsigned short u16x8;
typedef __attribute__((ext_vector_type(4))) float f32x4;

#define B_ 64
#define N_ 1024
#define C_ 128

static __device__ __forceinline__ unsigned short f2bf(float f) {  // RNE
  union { float f; unsigned int i; } v; v.f = f;
  unsigned int i = v.i;
  return (unsigned short)((i + 0x7FFFu + ((i >> 16) & 1u)) >> 16);
}
// truncation split: x = hi + lo + eps, |eps| <= 2^-17 |x|
static __device__ __forceinline__ void split1(float x, ushort_t& h, ushort_t& l) {
  union { float f; unsigned int i; } u; u.f = x;
  h = (ushort_t)(u.i >> 16);
  union { unsigned int i; float f; } t; t.i = u.i & 0xFFFF0000u;
  union { float f; unsigned int i; } w; w.f = x - t.f;
  l = (ushort_t)(w.i >> 16);
}
static __device__ __forceinline__ bf16x8 as_bf(u16x8 v) {
  union { u16x8 u; bf16x8 b; } x; x.u = v; return x.b;
}
static __device__ __forceinline__ void gload_lds16(const void* g, void* l) {
  __builtin_amdgcn_global_load_lds((const __attribute__((address_space(1))) void*)g,
                                   (__attribute__((address_space(3))) void*)l,
                                   16, 0, 0);
}

// ---------------------------------------------------------------------------
// Transpose + split: src fp32 [rows][cols] -> dh/dl bf16 [cols][rows]
// ---------------------------------------------------------------------------
__global__ __launch_bounds__(256) void tsplit(const float* __restrict__ src,
                                              ushort_t* __restrict__ dh,
                                              ushort_t* __restrict__ dl,
                                              int rows, int cols, long sb, long db) {
  __shared__ float tile[64][65];
  const int t = threadIdx.x;
  src += (long)blockIdx.z * sb;
  dh  += (long)blockIdx.z * db;
  dl  += (long)blockIdx.z * db;
  const int r0 = blockIdx.y * 64, c0 = blockIdx.x * 64;
#pragma unroll
  for (int p = 0; p < 4; ++p) {
    int row = p * 16 + (t >> 4), c4 = (t & 15) * 4;
    f32x4 v = *(const f32x4*)(src + (long)(r0 + row) * cols + c0 + c4);
#pragma unroll
    for (int j = 0; j < 4; ++j) tile[row][c4 + j] = v[j];
  }
  __syncthreads();
  const int oc = t >> 2;
#pragma unroll
  for (int p = 0; p < 2; ++p) {
    int ck = (t & 3) + p * 4;
    u16x8 vh, vl;
#pragma unroll
    for (int j = 0; j < 8; ++j) {
      ushort_t hj, lj;
      split1(tile[ck * 8 + j][oc], hj, lj);
      vh[j] = hj; vl[j] = lj;
    }
    long o = (long)(c0 + oc) * rows + r0 + ck * 8;
    *(u16x8*)(dh + o) = vh;
    *(u16x8*)(dl + o) = vl;
  }
}

// ---------------------------------------------------------------------------
// Fused GC GEMM + GRU.
// Phase 1 (GC): v = adj[b] @ ann[b] + bias, 128x128 tile, 4 waves, BK=64.
//   A (adj fp32) reg-staged+split into XOR-swizzled LDS hi/lo; B (annT pre-
//   split) via global_load_lds with pre-swizzled source. 3-term split MFMA.
// Phase 2: acc -> LDS fp32 [128][132] (pad keeps b128 reads uniform).
// Phase 3 (GRU): x frags from LDS (split at read), h frags from ann (global),
//   weights from L2; fused sigmoid/tanh epilogue writes out directly.
// XCD-chunked block swizzle: 8 consecutive batches per XCD -> annT L2-hits.
// ---------------------------------------------------------------------------
__global__ __launch_bounds__(256, 2) void gc_gru(const float* __restrict__ adj,
                                                 const ushort_t* __restrict__ annTh,
                                                 const ushort_t* __restrict__ annTl,
                                                 const float* __restrict__ ann,
                                                 const float* __restrict__ gcb,
                                                 const ushort_t* __restrict__ kTh,
                                                 const ushort_t* __restrict__ kTl,
                                                 const ushort_t* __restrict__ rTh,
                                                 const float* __restrict__ gb,
                                                 float* __restrict__ out) {
  __shared__ __align__(16) float vlds[128 * 132];     // 67.6 KB
  ushort_t* ldsAh = (ushort_t*)vlds;                  // GC staging aliases (64 KB)
  ushort_t* ldsAl = ldsAh + 128 * 64;
  ushort_t* ldsBh = ldsAl + 128 * 64;
  ushort_t* ldsBl = ldsBh + 128 * 64;

  const int tid = threadIdx.x;
  const int w = tid >> 6, lane = tid & 63;
  const int wr = w >> 1, wc = w & 1;
  // XCD-chunked swizzle (grid=512, 512%8==0 -> bijective)
  const int swz = (blockIdx.x & 7) * 64 + (blockIdx.x >> 3);
  const int b = swz >> 3;
  const int m0 = (swz & 7) * 128;

  const float*    adjb = adj   + ((long)b * N_ + m0) * N_;  // [128][1024] fp32
  const ushort_t* aThb = annTh + (long)b * C_ * N_;         // [128][1024] bf16
  const ushort_t* aTlb = annTl + (long)b * C_ * N_;

  const int srow8 = lane >> 3;
  const int klog  = ((lane & 7) * 16) ^ (srow8 << 4);  // pre-swizzled src byte off
  const int fr = lane & 15;
  const int kg = lane >> 4;

  f32x4 acc[4][4] = {};

  for (int k0 = 0; k0 < N_; k0 += 64) {
    // B staging: direct-to-LDS, source address carries the XOR swizzle
#pragma unroll
    for (int jj = 0; jj < 4; ++jj) {
      int j = w * 4 + jj;
      long so = (long)(j * 8 + srow8) * N_ + k0 + (klog >> 1);
      gload_lds16(aThb + so, (void*)&ldsBh[j * 512]);
      gload_lds16(aTlb + so, (void*)&ldsBl[j * 512]);
    }
    // A staging: fp32 load -> split -> swizzled ds_write
#pragma unroll
    for (int q = 0; q < 4; ++q) {
      int ch = q * 256 + tid;
      int row = ch >> 3, ce = ch & 7;
      const float* g = adjb + (long)row * N_ + k0 + ce * 8;
      f32x4 a0 = *(const f32x4*)g;
      f32x4 a1 = *(const f32x4*)(g + 4);
      u16x8 vh, vl;
#pragma unroll
      for (int j = 0; j < 4; ++j) {
        ushort_t hj, lj;
        split1(a0[j], hj, lj); vh[j] = hj; vl[j] = lj;
        split1(a1[j], hj, lj); vh[4 + j] = hj; vl[4 + j] = lj;
      }
      int kb = (ce * 16) ^ ((row & 7) << 4);
      *(u16x8*)((char*)ldsAh + row * 128 + kb) = vh;
      *(u16x8*)((char*)ldsAl + row * 128 + kb) = vl;
    }
    __syncthreads();
#pragma unroll
    for (int kk = 0; kk < 2; ++kk) {
      bf16x8 ah[4], al[4], bh[4], bl[4];
#pragma unroll
      for (int mi = 0; mi < 4; ++mi) {
        int row = wr * 64 + mi * 16 + fr;
        int kb = (kk * 64 + kg * 16) ^ ((row & 7) << 4);
        ah[mi] = *(const bf16x8*)((const char*)ldsAh + row * 128 + kb);
        al[mi] = *(const bf16x8*)((const char*)ldsAl + row * 128 + kb);
      }
#pragma unroll
      for (int ni = 0; ni < 4; ++ni) {
        int row = wc * 64 + ni * 16 + fr;
        int kb = (kk * 64 + kg * 16) ^ ((row & 7) << 4);
        bh[ni] = *(const bf16x8*)((const char*)ldsBh + row * 128 + kb);
        bl[ni] = *(const bf16x8*)((const char*)ldsBl + row * 128 + kb);
      }
#pragma unroll
      for (int mi = 0; mi < 4; ++mi)
#pragma unroll
        for (int ni = 0; ni < 4; ++ni) {
          acc[mi][ni] = __builtin_amdgcn_mfma_f32_16x16x32_bf16(ah[mi], bh[ni], acc[mi][ni], 0, 0, 0);
          acc[mi][ni] = __builtin_amdgcn_mfma_f32_16x16x32_bf16(al[mi], bh[ni], acc[mi][ni], 0, 0, 0);
          acc[mi][ni] = __builtin_amdgcn_mfma_f32_16x16x32_bf16(ah[mi], bl[ni], acc[mi][ni], 0, 0, 0);
        }
    }
    __syncthreads();
  }

  // ---- Phase 2: v (=acc+bias) -> LDS fp32, stride 132 ----
#pragma unroll
  for (int ni = 0; ni < 4; ++ni) {
    int col = wc * 64 + ni * 16 + fr;
    float bias = gcb[col];
#pragma unroll
    for (int mi = 0; mi < 4; ++mi) {
      int row = wr * 64 + mi * 16 + kg * 4;
#pragma unroll
      for (int r = 0; r < 4; ++r)
        vlds[(row + r) * 132 + col] = acc[mi][ni][r] + bias;
    }
  }
  __syncthreads();

  // ---- Phase 3: GRU. wave w owns block rows [w*32, w*32+32) ----
  const long grow = (long)b * N_ + m0 + w * 32;  // global row base of this wave

  bf16x8 xh[2][4], xl[2][4], hh[2][4];
#pragma unroll
  for (int s = 0; s < 2; ++s)
#pragma unroll
    for (int kk = 0; kk < 4; ++kk) {
      int lrow = w * 32 + s * 16 + fr;
      int k0 = kk * 32 + kg * 8;
      f32x4 x0 = *(const f32x4*)&vlds[lrow * 132 + k0];
      f32x4 x1 = *(const f32x4*)&vlds[lrow * 132 + k0 + 4];
      u16x8 th, tl;
#pragma unroll
      for (int j = 0; j < 4; ++j) {
        ushort_t hj, lj;
        split1(x0[j], hj, lj); th[j] = hj; tl[j] = lj;
        split1(x1[j], hj, lj); th[4 + j] = hj; tl[4 + j] = lj;
      }
      xh[s][kk] = as_bf(th); xl[s][kk] = as_bf(tl);
      const float* hrow = ann + (grow + s * 16 + fr) * C_ + k0;
      f32x4 h0 = *(const f32x4*)hrow;
      f32x4 h1 = *(const f32x4*)(hrow + 4);
      u16x8 hv;
#pragma unroll
      for (int j = 0; j < 4; ++j) { hv[j] = f2bf(h0[j]); hv[4 + j] = f2bf(h1[j]); }
      hh[s][kk] = as_bf(hv);
    }

#define GATE(G, AK0, AK1, AR0, AR1)                                                         \
  do {                                                                                      \
    const ushort_t* kh_ = kTh + (long)((G) * C_ + cb) * C_;                                 \
    const ushort_t* kl_ = kTl + (long)((G) * C_ + cb) * C_;                                 \
    const ushort_t* rh_ = rTh + (long)((G) * C_ + cb) * C_;                                 \
    bf16x8 KH[4], KL[4], RH[4];                                                             \
    _Pragma("unroll")                                                                       \
    for (int kk = 0; kk < 4; ++kk) {                                                        \
      int o_ = kk * 32 + kg * 8;                                                            \
      KH[kk] = *(const bf16x8*)(kh_ + o_);                                                  \
      KL[kk] = *(const bf16x8*)(kl_ + o_);                                                  \
      RH[kk] = *(const bf16x8*)(rh_ + o_);                                                  \
    }                                                                                       \
    _Pragma("unroll")                                                                       \
    for (int kk = 0; kk < 4; ++kk) {                                                        \
      AK0 = __builtin_amdgcn_mfma_f32_16x16x32_bf16(xh[0][kk], KH[kk], AK0, 0, 0, 0);       \
      AK1 = __builtin_amdgcn_mfma_f32_16x16x32_bf16(xh[1][kk], KH[kk], AK1, 0, 0, 0);       \
      AK0 = __builtin_amdgcn_mfma_f32_16x16x32_bf16(xl[0][kk], KH[kk], AK0, 0, 0, 0);       \
      AK1 = __builtin_amdgcn_mfma_f32_16x16x32_bf16(xl[1][kk], KH[kk], AK1, 0, 0, 0);       \
      AK0 = __builtin_amdgcn_mfma_f32_16x16x32_bf16(xh[0][kk], KL[kk], AK0, 0, 0, 0);       \
      AK1 = __builtin_amdgcn_mfma_f32_16x16x32_bf16(xh[1][kk], KL[kk], AK1, 0, 0, 0);       \
    }                                                                                       \
    _Pragma("unroll")                                                                       \
    for (int kk = 0; kk < 4; ++kk) {                                                        \
      AR0 = __builtin_amdgcn_mfma_f32_16x16x32_bf16(hh[0][kk], RH[kk], AR0, 0, 0, 0);       \
      AR1 = __builtin_amdgcn_mfma_f32_16x16x32_bf16(hh[1][kk], RH[kk], AR1, 0, 0, 0);       \
    }                                                                                       \
  } while (0)

#pragma unroll 1
  for (int n = 0; n < 8; ++n) {
    const int cb = n * 16 + fr;
    f32x4 az0 = {}, az1 = {}, ar0 = {}, ar1 = {}, ax0 = {}, ax1 = {}, ah0 = {}, ah1 = {};
    GATE(0, az0, az1, az0, az1);
    GATE(1, ar0, ar1, ar0, ar1);
    GATE(2, ax0, ax1, ah0, ah1);

    const float bz  = gb[cb] + gb[384 + cb];
    const float brr = gb[128 + cb] + gb[384 + 128 + cb];
    const float bxh = gb[256 + cb];
    const float bhi = gb[384 + 256 + cb];
#pragma unroll
    for (int s = 0; s < 2; ++s) {
      const f32x4& az_ = s ? az1 : az0;
      const f32x4& ar_ = s ? ar1 : ar0;
      const f32x4& ax_ = s ? ax1 : ax0;
      const f32x4& ah_ = s ? ah1 : ah0;
#pragma unroll
      for (int r = 0; r < 4; ++r) {
        long row = grow + s * 16 + kg * 4 + r;
        float hval = ann[row * C_ + cb];
        float zz = 1.f / (1.f + __expf(-(az_[r] + bz)));
        float rr = 1.f / (1.f + __expf(-(ar_[r] + brr)));
        float hpre = ax_[r] + bxh + rr * (ah_[r] + bhi);
        hpre = fminf(fmaxf(hpre, -15.f), 15.f);
        float e2 = __expf(2.f * hpre);
        float th = (e2 - 1.f) / (e2 + 1.f);
        out[row * C_ + cb] = zz * hval + (1.f - zz) * th;
      }
    }
  }
#undef GATE
}

// ---------------------------------------------------------------------------
extern "C" void kernel_launch(void* const* d_in, const int* in_sizes, int n_in,
                              void* d_out, int out_size, void* d_ws, size_t ws_size,
                              hipStream_t stream) {
  const float* adj = (const float*)d_in[0];
  const float* ann = (const float*)d_in[1];
  const float* gcb = (const float*)d_in[2];
  const float* ker = (const float*)d_in[3];
  const float* rk  = (const float*)d_in[4];
  const float* gb  = (const float*)d_in[5];
  float* out = (float*)d_out;

  char* ws = (char*)d_ws;
  ushort_t* annTh = (ushort_t*)(ws);                      // [64][128][1024] bf16, 16 MB
  ushort_t* annTl = (ushort_t*)(ws + 16777216);           // 16 MB
  ushort_t* kTh   = (ushort_t*)(ws + 33554432);           // [384][128]
  ushort_t* kTl   = (ushort_t*)(ws + 33652736);
  ushort_t* rTh   = (ushort_t*)(ws + 33751040);
  ushort_t* rTl   = (ushort_t*)(ws + 33849344);

  // ann [b][1024][128] -> annT hi/lo [b][128][1024]
  hipLaunchKernelGGL(tsplit, dim3(2, 16, 64), dim3(256), 0, stream,
                     ann, annTh, annTl, 1024, 128, (long)1024 * 128, (long)128 * 1024);
  // kernel/recurrent [128][384] -> [384][128] hi/lo
  hipLaunchKernelGGL(tsplit, dim3(6, 2, 1), dim3(256), 0, stream,
                     ker, kTh, kTl, 128, 384, 0L, 0L);
  hipLaunchKernelGGL(tsplit, dim3(6, 2, 1), dim3(256), 0, stream,
                     rk, rTh, rTl, 128, 384, 0L, 0L);
  // fused graph-conv + GRU
  hipLaunchKernelGGL(gc_gru, dim3(512), dim3(256), 0, stream,
                     adj, annTh, annTl, ann, gcb, kTh, kTl, rTh, gb, out);
}